// Round 14
// baseline (215.907 us; speedup 1.0000x reference)
//
#include <hip/hip_runtime.h>
#include <hip/hip_bf16.h>
#include <math.h>

typedef float floatx4 __attribute__((ext_vector_type(4)));
typedef short short8 __attribute__((ext_vector_type(8)));

#define IN_DIM 128
#define OUT_DIM 64
#define OWNER(d) (((d) >> 4) & 7)   // fallback-scatter XCD ownership
#define CHUNK 2048                   // fallback scatter chunk
#define CAP 32        // ssort slots/node; P(Poisson(16)>32) ~ 2e-4
#define OVF_CAP 8192  // exact overflow path
#define WPAD 136      // ushort row stride for W in LDS (gemm)
// R7/R8: binning beats atomic scatter. R12: NBIN=512 (2 blocks/CU) WON.
// R13 lesson: k_node is MEMORY-bound on the random z gather; its dur tracks
// achieved-BW variance (2.08 vs 1.66 TB/s run-to-run), judge edits by
// FETCH_SIZE and VALUBusy*dur. This round: gemm and bin are independent ->
// fuse as role-split grid (bin blocks FIRST so they drain under gemm tail).
// Gemm keeps its LDS (R7 failure was W-from-global); no launch-bounds (R2).
// cursor zeroing back to hipMemsetAsync: gemm-prologue zeroing would race
// with concurrent bin spill-markers.
#define NBIN 512
#define NB_SHIFT 8
#define CELL_CAP 18
#define SPILL_BIT (1 << 20)

__device__ __forceinline__ unsigned short bf16_rne(float f) {
    unsigned u = __float_as_uint(f);
    u += 0x7FFFu + ((u >> 16) & 1u);
    return (unsigned short)(u >> 16);
}
__device__ __forceinline__ float bf16_tof(unsigned short b) {
    return __uint_as_float(((unsigned)b) << 16);
}

// ---------------------------------------------------------------------------
// Fused front: role-split grid. Blocks [0, NBIN): edge binning (R8/R12 body).
// Blocks [NBIN, NBIN+nG): MFMA split-precision GEMM (R5-exact body, verified
// absmax 0.00390625). No data dependency between roles; different resources
// (edge stream + LDS atomics vs h stream + MFMA) -> wall time ~max not sum.
// ---------------------------------------------------------------------------
__global__ __launch_bounds__(256) void k_front(
    const float* __restrict__ h, const float* __restrict__ W,
    const float* __restrict__ a, __hip_bfloat16* __restrict__ z,
    float* __restrict__ s_src, float* __restrict__ s_dst, int N, int nG,
    const int* __restrict__ src, const int* __restrict__ dst,
    int* __restrict__ cursor, unsigned* __restrict__ bdata,
    int* __restrict__ bcnt, int* __restrict__ ovfcnt,
    int2* __restrict__ ovf, int E, int NB, int epb)
{
    __shared__ __align__(16) unsigned short sWhi[64 * WPAD];
    __shared__ __align__(16) unsigned short sWlo[64 * WPAD];
    __shared__ int cell[512];

    const int tid = threadIdx.x;
    const int b = blockIdx.x;

    if (b < NBIN) {
        // ------------------------- BIN role -------------------------
        for (int i = tid; i < NB; i += 256) cell[i] = 0;
        __syncthreads();

        const int c = b;
        const int e0 = c * epb;
        const int e1 = min(e0 + epb, E);
        const size_t cbase = (size_t)c * NB * CELL_CAP;
        for (int e = e0 + tid; e < e1; e += 256) {
            int d = __builtin_nontemporal_load(&dst[e]);
            int s = __builtin_nontemporal_load(&src[e]);
            int bk = d >> NB_SHIFT;
            int slot = atomicAdd(&cell[bk], 1);
            if (slot < CELL_CAP) {
                bdata[cbase + (size_t)bk * CELL_CAP + slot] =
                    ((unsigned)s << NB_SHIFT) |
                    (unsigned)(d & ((1 << NB_SHIFT) - 1));
            } else {
                atomicAdd(&cursor[d], SPILL_BIT);
                int op = atomicAdd(ovfcnt, 1);
                if (op < OVF_CAP) ovf[op] = make_int2(s, d);
            }
        }
        __syncthreads();
        for (int bk = tid; bk < NB; bk += 256) bcnt[c * NB + bk] = cell[bk];
        return;
    }

    // ------------------------- GEMM role -------------------------
    const int g = b - NBIN;
    if (g >= nG) return;

#pragma unroll
    for (int i = 0; i < 32; ++i) {
        int gg = tid + 256 * i;           // 0..8191
        float f = W[gg];
        int row = gg >> 7, k = gg & 127;
        unsigned short hb = bf16_rne(f);
        sWhi[row * WPAD + k] = hb;
        sWlo[row * WPAD + k] = bf16_rne(f - bf16_tof(hb));
    }

    const int wave = tid >> 6;
    const int l = tid & 63;
    const int lr = l & 15;                // A/B row-in-tile; C/D col
    const int lk = l >> 4;                // k-group / C/D row-group
    const int n0w = g * 64 + wave * 16;

    const int arow = min(n0w + lr, N - 1);   // clamp: garbage rows never stored
    const float* hrow = h + (size_t)arow * IN_DIM;
    short8 ahi[4], alo[4];
#pragma unroll
    for (int ks = 0; ks < 4; ++ks) {
        int k0 = 32 * ks + 8 * lk;
        floatx4 f0 = *(const floatx4*)(hrow + k0);
        floatx4 f1 = *(const floatx4*)(hrow + k0 + 4);
        float fv[8] = {f0.x, f0.y, f0.z, f0.w, f1.x, f1.y, f1.z, f1.w};
#pragma unroll
        for (int j = 0; j < 8; ++j) {
            unsigned short hb = bf16_rne(fv[j]);
            ahi[ks][j] = (short)hb;
            alo[ks][j] = (short)bf16_rne(fv[j] - bf16_tof(hb));
        }
    }
    __syncthreads();

    float ps[4] = {0.f, 0.f, 0.f, 0.f};
    float pd[4] = {0.f, 0.f, 0.f, 0.f};
#pragma unroll
    for (int ct = 0; ct < 4; ++ct) {
        floatx4 acc = (floatx4){0.f, 0.f, 0.f, 0.f};
#pragma unroll
        for (int ks = 0; ks < 4; ++ks) {
            const int boff = (ct * 16 + lr) * WPAD + 32 * ks + 8 * lk;
            short8 bhi = *(const short8*)&sWhi[boff];
            short8 blo = *(const short8*)&sWlo[boff];
            acc = __builtin_amdgcn_mfma_f32_16x16x32_bf16(ahi[ks], bhi, acc, 0, 0, 0);
            acc = __builtin_amdgcn_mfma_f32_16x16x32_bf16(alo[ks], bhi, acc, 0, 0, 0);
            acc = __builtin_amdgcn_mfma_f32_16x16x32_bf16(ahi[ks], blo, acc, 0, 0, 0);
        }
        const float asv = a[ct * 16 + lr];
        const float adv = a[OUT_DIM + ct * 16 + lr];
#pragma unroll
        for (int r = 0; r < 4; ++r) {
            int n = n0w + lk * 4 + r;
            if (n < N)
                z[(size_t)n * OUT_DIM + ct * 16 + lr] = __float2bfloat16(acc[r]);
            ps[r] += acc[r] * asv;
            pd[r] += acc[r] * adv;
        }
    }
#pragma unroll
    for (int r = 0; r < 4; ++r) {
#pragma unroll
        for (int off = 1; off <= 8; off <<= 1) {
            ps[r] += __shfl_xor(ps[r], off);
            pd[r] += __shfl_xor(pd[r], off);
        }
        int n = n0w + lk * 4 + r;
        if (lr == 0 && n < N) {
            s_src[n] = ps[r];
            s_dst[n] = pd[r];
        }
    }
}

// ---------------------------------------------------------------------------
// Phase 2: one block per bucket = sole owner of 256 contiguous nodes (R8).
// ---------------------------------------------------------------------------
__global__ __launch_bounds__(256) void k_fill(
    const unsigned* __restrict__ bdata, const int* __restrict__ bcnt,
    int* __restrict__ cursor, int* __restrict__ ssort,
    int* __restrict__ ovfcnt, int2* __restrict__ ovf,
    int nb1, int NB, int N)
{
    __shared__ int lcur[256];
    const int tid = threadIdx.x;
    lcur[tid] = 0;
    __syncthreads();

    const int b = blockIdx.x;
    const int n0 = b << NB_SHIFT;
    for (int c = tid; c < nb1; c += 256) {
        int cnt = min(bcnt[c * NB + b], CELL_CAP);
        size_t base = ((size_t)c * NB + b) * CELL_CAP;
        for (int j = 0; j < cnt; ++j) {
            unsigned v = bdata[base + j];
            int i = (int)(v & ((1u << NB_SHIFT) - 1));
            int s = (int)(v >> NB_SHIFT);
            int slot = atomicAdd(&lcur[i], 1);
            if (slot < CAP) {
                ssort[(n0 + i) * CAP + slot] = s;
            } else {
                int op = atomicAdd(ovfcnt, 1);
                if (op < OVF_CAP) ovf[op] = make_int2(s, n0 + i);
            }
        }
    }
    __syncthreads();
    int n = n0 + tid;
    if (n < N) {
        int v = lcur[tid];
        if (v) cursor[n] += v;    // sole owner; spill bits preserved
    }
}

// ---------------------------------------------------------------------------
// Fallback path kernels (small workspaces): plain gemm + R0 scatter.
// ---------------------------------------------------------------------------
__global__ __launch_bounds__(256) void k_gemm(
    const float* __restrict__ h, const float* __restrict__ W,
    const float* __restrict__ a, __hip_bfloat16* __restrict__ z,
    float* __restrict__ s_src, float* __restrict__ s_dst, int N)
{
    __shared__ __align__(16) unsigned short sWhi[64 * WPAD];
    __shared__ __align__(16) unsigned short sWlo[64 * WPAD];

    const int tid = threadIdx.x;
#pragma unroll
    for (int i = 0; i < 32; ++i) {
        int g = tid + 256 * i;
        float f = W[g];
        int row = g >> 7, k = g & 127;
        unsigned short hb = bf16_rne(f);
        sWhi[row * WPAD + k] = hb;
        sWlo[row * WPAD + k] = bf16_rne(f - bf16_tof(hb));
    }

    const int wave = tid >> 6;
    const int l = tid & 63;
    const int lr = l & 15;
    const int lk = l >> 4;
    const int n0w = blockIdx.x * 64 + wave * 16;

    const int arow = min(n0w + lr, N - 1);
    const float* hrow = h + (size_t)arow * IN_DIM;
    short8 ahi[4], alo[4];
#pragma unroll
    for (int ks = 0; ks < 4; ++ks) {
        int k0 = 32 * ks + 8 * lk;
        floatx4 f0 = *(const floatx4*)(hrow + k0);
        floatx4 f1 = *(const floatx4*)(hrow + k0 + 4);
        float fv[8] = {f0.x, f0.y, f0.z, f0.w, f1.x, f1.y, f1.z, f1.w};
#pragma unroll
        for (int j = 0; j < 8; ++j) {
            unsigned short hb = bf16_rne(fv[j]);
            ahi[ks][j] = (short)hb;
            alo[ks][j] = (short)bf16_rne(fv[j] - bf16_tof(hb));
        }
    }
    __syncthreads();

    float ps[4] = {0.f, 0.f, 0.f, 0.f};
    float pd[4] = {0.f, 0.f, 0.f, 0.f};
#pragma unroll
    for (int ct = 0; ct < 4; ++ct) {
        floatx4 acc = (floatx4){0.f, 0.f, 0.f, 0.f};
#pragma unroll
        for (int ks = 0; ks < 4; ++ks) {
            const int boff = (ct * 16 + lr) * WPAD + 32 * ks + 8 * lk;
            short8 bhi = *(const short8*)&sWhi[boff];
            short8 blo = *(const short8*)&sWlo[boff];
            acc = __builtin_amdgcn_mfma_f32_16x16x32_bf16(ahi[ks], bhi, acc, 0, 0, 0);
            acc = __builtin_amdgcn_mfma_f32_16x16x32_bf16(alo[ks], bhi, acc, 0, 0, 0);
            acc = __builtin_amdgcn_mfma_f32_16x16x32_bf16(ahi[ks], blo, acc, 0, 0, 0);
        }
        const float asv = a[ct * 16 + lr];
        const float adv = a[OUT_DIM + ct * 16 + lr];
#pragma unroll
        for (int r = 0; r < 4; ++r) {
            int n = n0w + lk * 4 + r;
            if (n < N)
                z[(size_t)n * OUT_DIM + ct * 16 + lr] = __float2bfloat16(acc[r]);
            ps[r] += acc[r] * asv;
            pd[r] += acc[r] * adv;
        }
    }
#pragma unroll
    for (int r = 0; r < 4; ++r) {
#pragma unroll
        for (int off = 1; off <= 8; off <<= 1) {
            ps[r] += __shfl_xor(ps[r], off);
            pd[r] += __shfl_xor(pd[r], off);
        }
        int n = n0w + lk * 4 + r;
        if (lr == 0 && n < N) {
            s_src[n] = ps[r];
            s_dst[n] = pd[r];
        }
    }
}

__global__ __launch_bounds__(256) void k_scatter(
    const int* __restrict__ src, const int* __restrict__ dst,
    int* __restrict__ cursor, int* __restrict__ ssort,
    int* __restrict__ ovfcnt, int2* __restrict__ ovf, int E)
{
    const int x = blockIdx.x & 7;
    const int c = blockIdx.x >> 3;
    const int e0 = c * CHUNK;
#pragma unroll
    for (int i = 0; i < CHUNK / 256; ++i) {
        int e = e0 + i * 256 + threadIdx.x;
        if (e < E) {
            int d = __builtin_nontemporal_load(&dst[e]);
            if (OWNER(d) == x) {
                int s = __builtin_nontemporal_load(&src[e]);
                int pos = atomicAdd(&cursor[d], 1);
                if (pos < CAP) {
                    ssort[d * CAP + pos] = s;
                } else {
                    int op = atomicAdd(ovfcnt, 1);
                    if (op < OVF_CAP) ovf[op] = make_int2(s, d);
                }
            }
        }
    }
}

// ---------------------------------------------------------------------------
// Fused per-node softmax + weighted gather + ELU -- R11-PROVEN BODY.
// Memory-bound on the z gather (R13: dur tracks achieved BW, FETCH const
// 85.4MB, VALU work const 34us). Keep predication (load-ILP scaffolding,
// R12 lesson) and this exact structure.
// ---------------------------------------------------------------------------
__global__ __launch_bounds__(256) void k_node(
    const int* __restrict__ cursor, const int* __restrict__ ssort,
    const float* __restrict__ s_src, const float* __restrict__ s_dst,
    const int* __restrict__ ovfcnt, const int2* __restrict__ ovf,
    const __hip_bfloat16* __restrict__ z, float* __restrict__ out, int N)
{
    const int lane = threadIdx.x & 63;
    const int wave = threadIdx.x >> 6;
    const int n = blockIdx.x * 4 + wave;
    if (n >= N) return;

    const int lg = lane >> 4;             // edge subgroup 0..3
    const int lc = lane & 15;             // col group: cols 4lc..4lc+3

    const int raw = cursor[n];
    if (raw == 0) {                       // empty segment -> elu(0) = 0
        if (lg == 0) {
            floatx4 zero = (floatx4){0.f, 0.f, 0.f, 0.f};
            __builtin_nontemporal_store(zero, (floatx4*)&out[(size_t)n * OUT_DIM + 4 * lc]);
        }
        return;
    }
    const int low = raw & 0xFFFFF;
    const int deg = min(low, CAP);
    const int base = n * CAP;
    const float sdn = s_dst[n];

    float sum = 0.f;
    int sv = 0;
    float ev = 0.f;
    {
        int kk = lane;
        if (kk < deg) {
            sv = __builtin_nontemporal_load(&ssort[base + kk]);
            float sc = s_src[sv] + sdn;
            sc = sc > 0.f ? sc : 0.01f * sc;   // leaky_relu
            ev = __expf(sc);
        }
        sum += ev;
    }

    floatx4 acc = (floatx4){0.f, 0.f, 0.f, 0.f};
    for (int j = 0; j < deg; j += 8) {
        int jj0 = j + lg, jj1 = j + 4 + lg;
        bool ok0 = jj0 < deg, ok1 = jj1 < deg;
        int s0 = __shfl(sv, ok0 ? jj0 : 0);
        int s1 = __shfl(sv, ok1 ? jj1 : 0);
        float w0 = __shfl(ev, ok0 ? jj0 : 0);
        float w1 = __shfl(ev, ok1 ? jj1 : 0);
        w0 = ok0 ? w0 : 0.f;
        w1 = ok1 ? w1 : 0.f;
        int sa0 = ok0 ? s0 : 0;
        int sa1 = ok1 ? s1 : 0;
        uint2 v0 = *(const uint2*)&z[(size_t)sa0 * OUT_DIM + 4 * lc];
        uint2 v1 = *(const uint2*)&z[(size_t)sa1 * OUT_DIM + 4 * lc];
        acc.x += w0 * __uint_as_float(v0.x << 16);
        acc.y += w0 * __uint_as_float(v0.x & 0xFFFF0000u);
        acc.z += w0 * __uint_as_float(v0.y << 16);
        acc.w += w0 * __uint_as_float(v0.y & 0xFFFF0000u);
        acc.x += w1 * __uint_as_float(v1.x << 16);
        acc.y += w1 * __uint_as_float(v1.x & 0xFFFF0000u);
        acc.z += w1 * __uint_as_float(v1.y << 16);
        acc.w += w1 * __uint_as_float(v1.y & 0xFFFF0000u);
    }
    acc.x += __shfl_xor(acc.x, 16); acc.y += __shfl_xor(acc.y, 16);
    acc.z += __shfl_xor(acc.z, 16); acc.w += __shfl_xor(acc.w, 16);
    acc.x += __shfl_xor(acc.x, 32); acc.y += __shfl_xor(acc.y, 32);
    acc.z += __shfl_xor(acc.z, 32); acc.w += __shfl_xor(acc.w, 32);

    if (raw > CAP) {
        int oc = min(*ovfcnt, OVF_CAP);
        for (int i = 0; i < oc; ++i) {
            int2 p = ovf[i];
            if (p.y == n) {
                float sc = s_src[p.x] + sdn;
                sc = sc > 0.f ? sc : 0.01f * sc;
                float e2 = __expf(sc);
                if (lane == 0) sum += e2;
                uint2 v = *(const uint2*)&z[(size_t)p.x * OUT_DIM + 4 * lc];
                acc.x += e2 * __uint_as_float(v.x << 16);
                acc.y += e2 * __uint_as_float(v.x & 0xFFFF0000u);
                acc.z += e2 * __uint_as_float(v.y << 16);
                acc.w += e2 * __uint_as_float(v.y & 0xFFFF0000u);
            }
        }
    }

#pragma unroll
    for (int off = 32; off >= 1; off >>= 1) sum += __shfl_xor(sum, off);

    if (lg == 0) {
        float inv = 1.f / sum;
        floatx4 o;
        o.x = acc.x * inv; o.y = acc.y * inv;
        o.z = acc.z * inv; o.w = acc.w * inv;
        o.x = o.x > 0.f ? o.x : __expf(o.x) - 1.f;   // ELU, alpha=1
        o.y = o.y > 0.f ? o.y : __expf(o.y) - 1.f;
        o.z = o.z > 0.f ? o.z : __expf(o.z) - 1.f;
        o.w = o.w > 0.f ? o.w : __expf(o.w) - 1.f;
        __builtin_nontemporal_store(o, (floatx4*)&out[(size_t)n * OUT_DIM + 4 * lc]);
    }
}

// ---------------------------------------------------------------------------
extern "C" void kernel_launch(void* const* d_in, const int* in_sizes, int n_in,
                              void* d_out, int out_size, void* d_ws, size_t ws_size,
                              hipStream_t stream)
{
    (void)n_in; (void)out_size;

    const float* h  = (const float*)d_in[0];
    const int* src  = (const int*)d_in[1];
    const int* dst  = (const int*)d_in[2];
    const float* W  = (const float*)d_in[3];
    const float* a  = (const float*)d_in[4];
    const int N = in_sizes[0] / IN_DIM;
    const int E = in_sizes[1];
    float* out = (float*)d_out;

    const int NB  = (N + (1 << NB_SHIFT) - 1) >> NB_SHIFT;
    const int nb1 = NBIN;                       // 512 = exactly 2 blocks/CU
    const int epb = (E + NBIN - 1) / NBIN;      // edges per bin block
    const int nG  = (N + 63) / 64;              // gemm blocks

    auto rnd = [](size_t b) { return (b + 255) & ~(size_t)255; };
    // meta: cursor[N] | ovfcnt | bcnt[nb1*NB]  (bcnt fully overwritten by bin)
    const size_t meta_ints = (size_t)N + 1 + (size_t)nb1 * NB;
    const size_t need_bucket =
        rnd((size_t)N * OUT_DIM * 2) + 2 * rnd((size_t)N * 4) +
        rnd(meta_ints * 4) + rnd((size_t)OVF_CAP * 8) +
        rnd((size_t)N * CAP * 4) + rnd((size_t)nb1 * NB * CELL_CAP * 4);
    const bool bucketed = (NB <= 512) && (need_bucket <= ws_size);

    char* wsp = (char*)d_ws;
    size_t off = 0;
    auto alloc = [&](size_t bytes) -> void* {
        void* p = wsp + off;
        off = (off + bytes + 255) & ~(size_t)255;
        return p;
    };
    __hip_bfloat16* z = (__hip_bfloat16*)alloc((size_t)N * OUT_DIM * 2);
    float* s_src = (float*)alloc((size_t)N * 4);
    float* s_dst = (float*)alloc((size_t)N * 4);

    if (bucketed) {
        int* cursor = (int*)alloc(meta_ints * 4);
        int* ovfcnt = cursor + N;
        int* bcnt   = cursor + N + 1;
        int2* ovf   = (int2*)alloc((size_t)OVF_CAP * 8);
        int* ssort  = (int*)alloc((size_t)N * CAP * 4);
        unsigned* bdata = (unsigned*)alloc((size_t)nb1 * NB * CELL_CAP * 4);

        // memset BEFORE k_front: bin spill-markers may touch cursor while
        // gemm blocks are still running (in-kernel zeroing would race)
        hipMemsetAsync(cursor, 0, (size_t)(N + 1) * 4, stream);
        k_front<<<NBIN + nG, 256, 0, stream>>>(h, W, a, z, s_src, s_dst, N, nG,
                                               src, dst, cursor, bdata, bcnt,
                                               ovfcnt, ovf, E, NB, epb);
        k_fill<<<NB, 256, 0, stream>>>(bdata, bcnt, cursor, ssort,
                                       ovfcnt, ovf, nb1, NB, N);
        k_node<<<(N + 3) / 4, 256, 0, stream>>>(cursor, ssort, s_src, s_dst,
                                                ovfcnt, ovf, z, out, N);
    } else {
        int* cursor = (int*)alloc((size_t)(N + 1) * 4);
        int* ovfcnt = cursor + N;
        int2* ovf   = (int2*)alloc((size_t)OVF_CAP * 8);
        int* ssort  = (int*)alloc((size_t)N * CAP * 4);

        const int nchunks = (E + CHUNK - 1) / CHUNK;
        hipMemsetAsync(cursor, 0, (size_t)(N + 1) * 4, stream);
        k_gemm<<<nG, 256, 0, stream>>>(h, W, a, z, s_src, s_dst, N);
        k_scatter<<<nchunks * 8, 256, 0, stream>>>(src, dst, cursor, ssort,
                                                   ovfcnt, ovf, E);
        k_node<<<(N + 3) / 4, 256, 0, stream>>>(cursor, ssort, s_src, s_dst,
                                                ovfcnt, ovf, z, out, N);
    }
}

// Round 15
// 207.803 us; speedup vs baseline: 1.0390x; 1.0390x over previous
//
#include <hip/hip_runtime.h>
#include <hip/hip_bf16.h>
#include <math.h>

typedef float floatx4 __attribute__((ext_vector_type(4)));
typedef short short8 __attribute__((ext_vector_type(8)));

#define IN_DIM 128
#define OUT_DIM 64
#define OWNER(d) (((d) >> 4) & 7)   // fallback-scatter XCD ownership
#define CHUNK 2048                   // fallback scatter chunk
#define CAP 32        // ssort slots/node; P(Poisson(16)>32) ~ 2e-4
#define OVF_CAP 8192  // exact overflow path
#define WPAD 136      // ushort row stride for W in LDS (gemm)
// R7/R8: binning beats atomic scatter. R12: NBIN=512 (2 blocks/CU) WON.
// R13: k_node is latency-exposed on the random z gather (FETCH const 85.4MB,
// achieved BW 1.7 TB/s << HBM; VALU ~34us const). R14: gemm||bin role-split
// fusion NEUTRAL->negative; fusion closed 0-for-3. This round: 4-deep load
// pipeline in k_node's gather (2 iters of 16 edges vs 4 of 8).
#define NBIN 512
#define NB_SHIFT 8
#define CELL_CAP 18
#define SPILL_BIT (1 << 20)

__device__ __forceinline__ unsigned short bf16_rne(float f) {
    unsigned u = __float_as_uint(f);
    u += 0x7FFFu + ((u >> 16) & 1u);
    return (unsigned short)(u >> 16);
}
__device__ __forceinline__ float bf16_tof(unsigned short b) {
    return __uint_as_float(((unsigned)b) << 16);
}

// ---------------------------------------------------------------------------
// MFMA GEMM (R5-exact, verified absmax 0.00390625): split-precision
// z = h@W^T via mfma_f32_16x16x32_bf16. Prologue zeroes meta (cursor|ovfcnt)
// -- safe: k_bin runs strictly after in stream order (separate dispatch).
// ---------------------------------------------------------------------------
__global__ __launch_bounds__(256) void k_gemm(
    const float* __restrict__ h, const float* __restrict__ W,
    const float* __restrict__ a, __hip_bfloat16* __restrict__ z,
    float* __restrict__ s_src, float* __restrict__ s_dst, int N,
    int* __restrict__ meta, int mcount)
{
    __shared__ __align__(16) unsigned short sWhi[64 * WPAD];
    __shared__ __align__(16) unsigned short sWlo[64 * WPAD];

    const int tid = threadIdx.x;
    for (int i = blockIdx.x * 256 + tid; i < mcount; i += gridDim.x * 256)
        meta[i] = 0;

#pragma unroll
    for (int i = 0; i < 32; ++i) {
        int g = tid + 256 * i;            // 0..8191
        float f = W[g];
        int row = g >> 7, k = g & 127;
        unsigned short hb = bf16_rne(f);
        sWhi[row * WPAD + k] = hb;
        sWlo[row * WPAD + k] = bf16_rne(f - bf16_tof(hb));
    }

    const int wave = tid >> 6;
    const int l = tid & 63;
    const int lr = l & 15;                // A/B row-in-tile; C/D col
    const int lk = l >> 4;                // k-group / C/D row-group
    const int n0w = blockIdx.x * 64 + wave * 16;

    const int arow = min(n0w + lr, N - 1);   // clamp: garbage rows never stored
    const float* hrow = h + (size_t)arow * IN_DIM;
    short8 ahi[4], alo[4];
#pragma unroll
    for (int ks = 0; ks < 4; ++ks) {
        int k0 = 32 * ks + 8 * lk;
        floatx4 f0 = *(const floatx4*)(hrow + k0);
        floatx4 f1 = *(const floatx4*)(hrow + k0 + 4);
        float fv[8] = {f0.x, f0.y, f0.z, f0.w, f1.x, f1.y, f1.z, f1.w};
#pragma unroll
        for (int j = 0; j < 8; ++j) {
            unsigned short hb = bf16_rne(fv[j]);
            ahi[ks][j] = (short)hb;
            alo[ks][j] = (short)bf16_rne(fv[j] - bf16_tof(hb));
        }
    }
    __syncthreads();

    float ps[4] = {0.f, 0.f, 0.f, 0.f};
    float pd[4] = {0.f, 0.f, 0.f, 0.f};
#pragma unroll
    for (int ct = 0; ct < 4; ++ct) {
        floatx4 acc = (floatx4){0.f, 0.f, 0.f, 0.f};
#pragma unroll
        for (int ks = 0; ks < 4; ++ks) {
            const int boff = (ct * 16 + lr) * WPAD + 32 * ks + 8 * lk;
            short8 bhi = *(const short8*)&sWhi[boff];
            short8 blo = *(const short8*)&sWlo[boff];
            acc = __builtin_amdgcn_mfma_f32_16x16x32_bf16(ahi[ks], bhi, acc, 0, 0, 0);
            acc = __builtin_amdgcn_mfma_f32_16x16x32_bf16(alo[ks], bhi, acc, 0, 0, 0);
            acc = __builtin_amdgcn_mfma_f32_16x16x32_bf16(ahi[ks], blo, acc, 0, 0, 0);
        }
        const float asv = a[ct * 16 + lr];
        const float adv = a[OUT_DIM + ct * 16 + lr];
#pragma unroll
        for (int r = 0; r < 4; ++r) {
            int n = n0w + lk * 4 + r;
            if (n < N)
                z[(size_t)n * OUT_DIM + ct * 16 + lr] = __float2bfloat16(acc[r]);
            ps[r] += acc[r] * asv;
            pd[r] += acc[r] * adv;
        }
    }
#pragma unroll
    for (int r = 0; r < 4; ++r) {
#pragma unroll
        for (int off = 1; off <= 8; off <<= 1) {
            ps[r] += __shfl_xor(ps[r], off);
            pd[r] += __shfl_xor(pd[r], off);
        }
        int n = n0w + lk * 4 + r;
        if (lr == 0 && n < N) {
            s_src[n] = ps[r];
            s_dst[n] = pd[r];
        }
    }
}

// ---------------------------------------------------------------------------
// Phase 1: single-scan LDS binning (R8-proven body; R12: grid=512 WON).
// ---------------------------------------------------------------------------
__global__ __launch_bounds__(256) void k_bin(
    const int* __restrict__ src, const int* __restrict__ dst,
    int* __restrict__ cursor, unsigned* __restrict__ bdata,
    int* __restrict__ bcnt, int* __restrict__ ovfcnt,
    int2* __restrict__ ovf, int E, int NB, int epb)
{
    __shared__ int cell[512];
    const int tid = threadIdx.x;
    for (int i = tid; i < NB; i += 256) cell[i] = 0;
    __syncthreads();

    const int c = blockIdx.x;
    const int e0 = c * epb;
    const int e1 = min(e0 + epb, E);
    const size_t cbase = (size_t)c * NB * CELL_CAP;
    for (int e = e0 + tid; e < e1; e += 256) {
        int d = __builtin_nontemporal_load(&dst[e]);
        int s = __builtin_nontemporal_load(&src[e]);
        int b = d >> NB_SHIFT;
        int slot = atomicAdd(&cell[b], 1);
        if (slot < CELL_CAP) {
            bdata[cbase + (size_t)b * CELL_CAP + slot] =
                ((unsigned)s << NB_SHIFT) |
                (unsigned)(d & ((1 << NB_SHIFT) - 1));
        } else {
            atomicAdd(&cursor[d], SPILL_BIT);
            int op = atomicAdd(ovfcnt, 1);
            if (op < OVF_CAP) ovf[op] = make_int2(s, d);
        }
    }
    __syncthreads();
    for (int b = tid; b < NB; b += 256) bcnt[c * NB + b] = cell[b];
}

// ---------------------------------------------------------------------------
// Phase 2: one block per bucket = sole owner of 256 contiguous nodes (R8).
// ---------------------------------------------------------------------------
__global__ __launch_bounds__(256) void k_fill(
    const unsigned* __restrict__ bdata, const int* __restrict__ bcnt,
    int* __restrict__ cursor, int* __restrict__ ssort,
    int* __restrict__ ovfcnt, int2* __restrict__ ovf,
    int nb1, int NB, int N)
{
    __shared__ int lcur[256];
    const int tid = threadIdx.x;
    lcur[tid] = 0;
    __syncthreads();

    const int b = blockIdx.x;
    const int n0 = b << NB_SHIFT;
    for (int c = tid; c < nb1; c += 256) {
        int cnt = min(bcnt[c * NB + b], CELL_CAP);
        size_t base = ((size_t)c * NB + b) * CELL_CAP;
        for (int j = 0; j < cnt; ++j) {
            unsigned v = bdata[base + j];
            int i = (int)(v & ((1u << NB_SHIFT) - 1));
            int s = (int)(v >> NB_SHIFT);
            int slot = atomicAdd(&lcur[i], 1);
            if (slot < CAP) {
                ssort[(n0 + i) * CAP + slot] = s;
            } else {
                int op = atomicAdd(ovfcnt, 1);
                if (op < OVF_CAP) ovf[op] = make_int2(s, n0 + i);
            }
        }
    }
    __syncthreads();
    int n = n0 + tid;
    if (n < N) {
        int v = lcur[tid];
        if (v) cursor[n] += v;    // sole owner; spill bits preserved
    }
}

// ---------------------------------------------------------------------------
// Fallback scatter (proven R0 82us body) for small workspaces.
// ---------------------------------------------------------------------------
__global__ __launch_bounds__(256) void k_scatter(
    const int* __restrict__ src, const int* __restrict__ dst,
    int* __restrict__ cursor, int* __restrict__ ssort,
    int* __restrict__ ovfcnt, int2* __restrict__ ovf, int E)
{
    const int x = blockIdx.x & 7;
    const int c = blockIdx.x >> 3;
    const int e0 = c * CHUNK;
#pragma unroll
    for (int i = 0; i < CHUNK / 256; ++i) {
        int e = e0 + i * 256 + threadIdx.x;
        if (e < E) {
            int d = __builtin_nontemporal_load(&dst[e]);
            if (OWNER(d) == x) {
                int s = __builtin_nontemporal_load(&src[e]);
                int pos = atomicAdd(&cursor[d], 1);
                if (pos < CAP) {
                    ssort[d * CAP + pos] = s;
                } else {
                    int op = atomicAdd(ovfcnt, 1);
                    if (op < OVF_CAP) ovf[op] = make_int2(s, d);
                }
            }
        }
    }
}

// ---------------------------------------------------------------------------
// Fused per-node softmax + weighted gather + ELU (R11 body + 4-deep MLP).
// R13/R14: latency-exposed (VALU ~34us + ~33us stall @ 2 loads in flight).
// Gather now runs j += 16 with FOUR independent z-row loads in flight
// (exactly 2 iterations at deg<=32). Predication kept: R12 showed it is
// the compiler's load-ILP scaffolding; FMA order per column unchanged.
// ---------------------------------------------------------------------------
__global__ __launch_bounds__(256) void k_node(
    const int* __restrict__ cursor, const int* __restrict__ ssort,
    const float* __restrict__ s_src, const float* __restrict__ s_dst,
    const int* __restrict__ ovfcnt, const int2* __restrict__ ovf,
    const __hip_bfloat16* __restrict__ z, float* __restrict__ out, int N)
{
    const int lane = threadIdx.x & 63;
    const int wave = threadIdx.x >> 6;
    const int n = blockIdx.x * 4 + wave;
    if (n >= N) return;

    const int lg = lane >> 4;             // edge subgroup 0..3
    const int lc = lane & 15;             // col group: cols 4lc..4lc+3

    const int raw = cursor[n];
    if (raw == 0) {                       // empty segment -> elu(0) = 0
        if (lg == 0) {
            floatx4 zero = (floatx4){0.f, 0.f, 0.f, 0.f};
            __builtin_nontemporal_store(zero, (floatx4*)&out[(size_t)n * OUT_DIM + 4 * lc]);
        }
        return;
    }
    const int low = raw & 0xFFFFF;
    const int deg = min(low, CAP);
    const int base = n * CAP;
    const float sdn = s_dst[n];

    // score phase: lane kk handles edge kk (deg <= 32 < 64: single pass)
    float sum = 0.f;
    int sv = 0;
    float ev = 0.f;
    {
        int kk = lane;
        if (kk < deg) {
            sv = __builtin_nontemporal_load(&ssort[base + kk]);
            float sc = s_src[sv] + sdn;
            sc = sc > 0.f ? sc : 0.01f * sc;   // leaky_relu
            ev = __expf(sc);
        }
        sum += ev;
    }

    // gather: 16 edges per iteration, 4 z-row loads in flight
    floatx4 acc = (floatx4){0.f, 0.f, 0.f, 0.f};
    for (int j = 0; j < deg; j += 16) {
        int jj0 = j + lg, jj1 = j + 4 + lg, jj2 = j + 8 + lg, jj3 = j + 12 + lg;
        bool ok0 = jj0 < deg, ok1 = jj1 < deg, ok2 = jj2 < deg, ok3 = jj3 < deg;
        int s0 = __shfl(sv, ok0 ? jj0 : 0);
        int s1 = __shfl(sv, ok1 ? jj1 : 0);
        int s2 = __shfl(sv, ok2 ? jj2 : 0);
        int s3 = __shfl(sv, ok3 ? jj3 : 0);
        float w0 = __shfl(ev, ok0 ? jj0 : 0);
        float w1 = __shfl(ev, ok1 ? jj1 : 0);
        float w2 = __shfl(ev, ok2 ? jj2 : 0);
        float w3 = __shfl(ev, ok3 ? jj3 : 0);
        w0 = ok0 ? w0 : 0.f;
        w1 = ok1 ? w1 : 0.f;
        w2 = ok2 ? w2 : 0.f;
        w3 = ok3 ? w3 : 0.f;
        int sa0 = ok0 ? s0 : 0;
        int sa1 = ok1 ? s1 : 0;
        int sa2 = ok2 ? s2 : 0;
        int sa3 = ok3 ? s3 : 0;
        uint2 v0 = *(const uint2*)&z[(size_t)sa0 * OUT_DIM + 4 * lc];
        uint2 v1 = *(const uint2*)&z[(size_t)sa1 * OUT_DIM + 4 * lc];
        uint2 v2 = *(const uint2*)&z[(size_t)sa2 * OUT_DIM + 4 * lc];
        uint2 v3 = *(const uint2*)&z[(size_t)sa3 * OUT_DIM + 4 * lc];
        acc.x += w0 * __uint_as_float(v0.x << 16);
        acc.y += w0 * __uint_as_float(v0.x & 0xFFFF0000u);
        acc.z += w0 * __uint_as_float(v0.y << 16);
        acc.w += w0 * __uint_as_float(v0.y & 0xFFFF0000u);
        acc.x += w1 * __uint_as_float(v1.x << 16);
        acc.y += w1 * __uint_as_float(v1.x & 0xFFFF0000u);
        acc.z += w1 * __uint_as_float(v1.y << 16);
        acc.w += w1 * __uint_as_float(v1.y & 0xFFFF0000u);
        acc.x += w2 * __uint_as_float(v2.x << 16);
        acc.y += w2 * __uint_as_float(v2.x & 0xFFFF0000u);
        acc.z += w2 * __uint_as_float(v2.y << 16);
        acc.w += w2 * __uint_as_float(v2.y & 0xFFFF0000u);
        acc.x += w3 * __uint_as_float(v3.x << 16);
        acc.y += w3 * __uint_as_float(v3.x & 0xFFFF0000u);
        acc.z += w3 * __uint_as_float(v3.y << 16);
        acc.w += w3 * __uint_as_float(v3.y & 0xFFFF0000u);
    }
    // fold the 4 edge subgroups: lanes sharing lc end with identical acc
    acc.x += __shfl_xor(acc.x, 16); acc.y += __shfl_xor(acc.y, 16);
    acc.z += __shfl_xor(acc.z, 16); acc.w += __shfl_xor(acc.w, 16);
    acc.x += __shfl_xor(acc.x, 32); acc.y += __shfl_xor(acc.y, 32);
    acc.z += __shfl_xor(acc.z, 32); acc.w += __shfl_xor(acc.w, 32);

    // exact overflow path (after fold: all lg-redundant lanes add identically)
    if (raw > CAP) {
        int oc = min(*ovfcnt, OVF_CAP);
        for (int i = 0; i < oc; ++i) {
            int2 p = ovf[i];
            if (p.y == n) {
                float sc = s_src[p.x] + sdn;
                sc = sc > 0.f ? sc : 0.01f * sc;
                float e2 = __expf(sc);
                if (lane == 0) sum += e2;
                uint2 v = *(const uint2*)&z[(size_t)p.x * OUT_DIM + 4 * lc];
                acc.x += e2 * __uint_as_float(v.x << 16);
                acc.y += e2 * __uint_as_float(v.x & 0xFFFF0000u);
                acc.z += e2 * __uint_as_float(v.y << 16);
                acc.w += e2 * __uint_as_float(v.y & 0xFFFF0000u);
            }
        }
    }

#pragma unroll
    for (int off = 32; off >= 1; off >>= 1) sum += __shfl_xor(sum, off);

    if (lg == 0) {
        float inv = 1.f / sum;
        floatx4 o;
        o.x = acc.x * inv; o.y = acc.y * inv;
        o.z = acc.z * inv; o.w = acc.w * inv;
        o.x = o.x > 0.f ? o.x : __expf(o.x) - 1.f;   // ELU, alpha=1
        o.y = o.y > 0.f ? o.y : __expf(o.y) - 1.f;
        o.z = o.z > 0.f ? o.z : __expf(o.z) - 1.f;
        o.w = o.w > 0.f ? o.w : __expf(o.w) - 1.f;
        __builtin_nontemporal_store(o, (floatx4*)&out[(size_t)n * OUT_DIM + 4 * lc]);
    }
}

// ---------------------------------------------------------------------------
extern "C" void kernel_launch(void* const* d_in, const int* in_sizes, int n_in,
                              void* d_out, int out_size, void* d_ws, size_t ws_size,
                              hipStream_t stream)
{
    (void)n_in; (void)out_size;

    const float* h  = (const float*)d_in[0];
    const int* src  = (const int*)d_in[1];
    const int* dst  = (const int*)d_in[2];
    const float* W  = (const float*)d_in[3];
    const float* a  = (const float*)d_in[4];
    const int N = in_sizes[0] / IN_DIM;
    const int E = in_sizes[1];
    float* out = (float*)d_out;

    const int NB  = (N + (1 << NB_SHIFT) - 1) >> NB_SHIFT;
    const int nb1 = NBIN;                       // 512 = exactly 2 blocks/CU
    const int epb = (E + NBIN - 1) / NBIN;      // edges per bin block

    auto rnd = [](size_t b) { return (b + 255) & ~(size_t)255; };
    // meta: cursor[N] | ovfcnt | bcnt[nb1*NB]  (bcnt fully overwritten by k_bin)
    const size_t meta_ints = (size_t)N + 1 + (size_t)nb1 * NB;
    const size_t need_bucket =
        rnd((size_t)N * OUT_DIM * 2) + 2 * rnd((size_t)N * 4) +
        rnd(meta_ints * 4) + rnd((size_t)OVF_CAP * 8) +
        rnd((size_t)N * CAP * 4) + rnd((size_t)nb1 * NB * CELL_CAP * 4);
    const bool bucketed = (NB <= 512) && (need_bucket <= ws_size);

    char* wsp = (char*)d_ws;
    size_t off = 0;
    auto alloc = [&](size_t bytes) -> void* {
        void* p = wsp + off;
        off = (off + bytes + 255) & ~(size_t)255;
        return p;
    };
    __hip_bfloat16* z = (__hip_bfloat16*)alloc((size_t)N * OUT_DIM * 2);
    float* s_src = (float*)alloc((size_t)N * 4);
    float* s_dst = (float*)alloc((size_t)N * 4);

    if (bucketed) {
        int* cursor = (int*)alloc(meta_ints * 4);
        int* ovfcnt = cursor + N;
        int* bcnt   = cursor + N + 1;
        int2* ovf   = (int2*)alloc((size_t)OVF_CAP * 8);
        int* ssort  = (int*)alloc((size_t)N * CAP * 4);
        unsigned* bdata = (unsigned*)alloc((size_t)nb1 * NB * CELL_CAP * 4);

        // gemm zeroes cursor|ovfcnt (N+1 ints); bcnt fully overwritten by k_bin
        k_gemm<<<(N + 63) / 64, 256, 0, stream>>>(h, W, a, z, s_src, s_dst, N,
                                                  cursor, N + 1);
        k_bin<<<nb1, 256, 0, stream>>>(src, dst, cursor, bdata, bcnt,
                                       ovfcnt, ovf, E, NB, epb);
        k_fill<<<NB, 256, 0, stream>>>(bdata, bcnt, cursor, ssort,
                                       ovfcnt, ovf, nb1, NB, N);
        k_node<<<(N + 3) / 4, 256, 0, stream>>>(cursor, ssort, s_src, s_dst,
                                                ovfcnt, ovf, z, out, N);
    } else {
        int* cursor = (int*)alloc((size_t)(N + 1) * 4);
        int* ovfcnt = cursor + N;
        int2* ovf   = (int2*)alloc((size_t)OVF_CAP * 8);
        int* ssort  = (int*)alloc((size_t)N * CAP * 4);

        const int nchunks = (E + CHUNK - 1) / CHUNK;
        k_gemm<<<(N + 63) / 64, 256, 0, stream>>>(h, W, a, z, s_src, s_dst, N,
                                                  cursor, N + 1);
        k_scatter<<<nchunks * 8, 256, 0, stream>>>(src, dst, cursor, ssort,
                                                   ovfcnt, ovf, E);
        k_node<<<(N + 3) / 4, 256, 0, stream>>>(cursor, ssort, s_src, s_dst,
                                                ovfcnt, ovf, z, out, N);
    }
}